// Round 28
// baseline (143.798 us; speedup 1.0000x reference)
//
#include <hip/hip_runtime.h>

// Model dims (fixed by the problem)
#define TT    128
#define CC    64
#define HH    4
#define SS    16
#define D4    256     // 4*C
#define HID_  256
#define VV    32000
#define NPE_  4
#define RR    256     // B*T
#define LOG2E 1.44269504f

typedef float f32x4 __attribute__((ext_vector_type(4)));

__device__ __forceinline__ float wred_sum(float v) {
#pragma unroll
    for (int off = 32; off; off >>= 1) v += __shfl_xor(v, off, 64);
    return v;
}
__device__ __forceinline__ float wred_max(float v) {
#pragma unroll
    for (int off = 32; off; off >>= 1) v = fmaxf(v, __shfl_xor(v, off, 64));
    return v;
}
__device__ __forceinline__ float sigm(float x) {
    return __builtin_amdgcn_rcpf(1.f + exp2f(-x * LOG2E));
}
__device__ __forceinline__ float sigm2(float t) {   // input pre-scaled by log2e
    return __builtin_amdgcn_rcpf(1.f + exp2f(-t));
}

// VALU-pipe 16-lane sum reduce via DPP row rotates (no DS ops)
#define DPP_ADD(v, ctrl)                                                       \
    v += __int_as_float(__builtin_amdgcn_update_dpp(                           \
        0, __float_as_int(v), ctrl, 0xF, 0xF, true))
__device__ __forceinline__ float row16_sum(float v) {
    DPP_ADD(v, 0x128);   // row_ror:8
    DPP_ADD(v, 0x124);   // row_ror:4
    DPP_ADD(v, 0x122);   // row_ror:2
    DPP_ADD(v, 0x121);   // row_ror:1
    return v;            // all 16 lanes hold the row sum
}

// ============ embed + all positional embeddings (one launch) ============
__global__ void k_embed_pos(const int* __restrict__ idx, const float* __restrict__ tok,
                            const float* __restrict__ pe_tab, const float* __restrict__ W1,
                            const float* __restrict__ b1, const float* __restrict__ W2,
                            const float* __restrict__ b2, const float* __restrict__ g,
                            const float* __restrict__ bb,
                            float* __restrict__ x, float* __restrict__ pos) {
    int blk = blockIdx.x, c = threadIdx.x;
    if (blk >= 512) {
        int r = blk - 512;
        x[r * CC + c] = tok[idx[r] * CC + c];
        return;
    }
    int p = blk >> 7, t = blk & 127;
    __shared__ float s_pe[CC], s_h[CC];
    s_pe[c] = pe_tab[(p * TT + t) * CC + c];
    __syncthreads();
    const float* w1 = W1 + p * CC * CC;
    float a = b1[p * CC + c];
    for (int k = 0; k < CC; k++) a += s_pe[k] * w1[k * CC + c];
    s_h[c] = sigm(a);
    __syncthreads();
    const float* w2 = W2 + p * CC * CC;
    float o = b2[p * CC + c];
    for (int k = 0; k < CC; k++) o += s_h[k] * w2[k * CC + c];
    float m = wred_sum(o) * (1.f / CC);
    float d = o - m;
    float var = wred_sum(d * d) * (1.f / CC);
    pos[(p * TT + t) * CC + c] =
        d * rsqrtf(var + 1e-5f) * g[p * CC + c] + bb[p * CC + c];
}

// ============ stage A v3b: 4 rows/block, 512 blocks; spill-guarded ==========
// rg = blk&63 (4 rows), kq = (blk>>6)&1, h = blk>>7
__global__ void __launch_bounds__(256, 4) k_stageA(
    const float* __restrict__ x, const float* __restrict__ pos_p,
    const float* __restrict__ ln1g, const float* __restrict__ ln1b,
    const float* __restrict__ attW1, const float* __restrict__ ab1,
    const float* __restrict__ valW,
    float* __restrict__ Kp, float* __restrict__ Qp, float* __restrict__ v) {
    int blk = blockIdx.x, tid = threadIdx.x;
    int lane = tid & 63, wv = tid >> 6;
    int rg = blk & 63, kq = (blk >> 6) & 1, h = blk >> 7;
    int r0 = rg * 4;
    __shared__ __align__(16) float x1[4][128];
    {   // LN1: wave wv handles row r0+wv
        float xv = x[(r0 + wv) * CC + lane];
        float m = wred_sum(xv) * (1.f / CC);
        float d = xv - m;
        float var = wred_sum(d * d) * (1.f / CC);
        x1[wv][64 + lane] = d * rsqrtf(var + 1e-5f) * ln1g[lane] + ln1b[lane];
    }
    {   // pos half: 256 threads = 4 rows x 64 cols
        int rr = tid >> 6, cc = tid & 63;
        int t = (r0 + rr) & (TT - 1);
        x1[rr][cc] = pos_p[t * CC + cc];
    }
    __syncthreads();
    const float* w = attW1 + (h * D4 + kq * 128) * D4 + tid;
    float a0 = 0, a1 = 0, a2 = 0, a3 = 0;
#pragma unroll 2
    for (int c = 0; c < 128; c += 4) {
        float4 xr0 = *(const float4*)&x1[0][c];
        float4 xr1 = *(const float4*)&x1[1][c];
        float4 xr2 = *(const float4*)&x1[2][c];
        float4 xr3 = *(const float4*)&x1[3][c];
        float w0 = w[(size_t)(c + 0) * D4];
        float w1 = w[(size_t)(c + 1) * D4];
        float w2 = w[(size_t)(c + 2) * D4];
        float w3 = w[(size_t)(c + 3) * D4];
        a0 += xr0.x * w0 + xr0.y * w1 + xr0.z * w2 + xr0.w * w3;
        a1 += xr1.x * w0 + xr1.y * w1 + xr1.z * w2 + xr1.w * w3;
        a2 += xr2.x * w0 + xr2.y * w1 + xr2.z * w2 + xr2.w * w3;
        a3 += xr3.x * w0 + xr3.y * w1 + xr3.z * w2 + xr3.w * w3;
    }
    float badd = kq ? 0.f : ab1[h * D4 + tid];   // fold b1 into K
    float* outKQ = kq ? Qp : Kp;
    outKQ[(h * RR + r0 + 0) * D4 + tid] = (a0 + badd) * LOG2E;
    outKQ[(h * RR + r0 + 1) * D4 + tid] = (a1 + badd) * LOG2E;
    outKQ[(h * RR + r0 + 2) * D4 + tid] = (a2 + badd) * LOG2E;
    outKQ[(h * RR + r0 + 3) * D4 + tid] = (a3 + badd) * LOG2E;
    if (kq == 0 && tid < 64) {   // V: 4 rows x 16 s
        int rr = tid >> 4, s = tid & 15;
        const float* wvw = valW + h * CC * SS;
        float a = 0.f;
#pragma unroll 8
        for (int k = 0; k < CC; k++) a += x1[rr][64 + k] * wvw[k * SS + s];
        v[(h * RR + r0 + rr) * SS + s] = a;
    }
}

// ============ att4: causal-balanced row pairs (i, 127-i), 16 waves/CU ======
// 512 blocks x 512 thr; pairIdx = bid&63, bat = (bid>>6)&1, h = bid>>7
__global__ void __launch_bounds__(512) k_att4(
    const float* __restrict__ Kp, const float* __restrict__ Qp,
    const float* __restrict__ v,
    const float* __restrict__ aw2, const float* __restrict__ ab2,
    float* __restrict__ o) {
    int bid = blockIdx.x;
    int pairIdx = bid & 63, bat = (bid >> 6) & 1, h = bid >> 7;
    int iA = pairIdx, iB = 127 - pairIdx;
    int tid = threadIdx.x, lane = tid & 63, wv = tid >> 6;   // wv 0..7
    __shared__ float sc[2][TT];
    __shared__ float part[2][16][17];
    int sub = lane >> 4;                       // j sub-slot within wave
    int dlo = (lane & 15) * 16;                // 16 d-components per lane
    const float* wrow = aw2 + h * D4 + dlo;
    float4 w0 = *(const float4*)(wrow + 0);
    float4 w1 = *(const float4*)(wrow + 4);
    float4 w2 = *(const float4*)(wrow + 8);
    float4 w3 = *(const float4*)(wrow + 12);
    const float sc8 = 0.125f;
    w0.x *= sc8; w0.y *= sc8; w0.z *= sc8; w0.w *= sc8;
    w1.x *= sc8; w1.y *= sc8; w1.z *= sc8; w1.w *= sc8;
    w2.x *= sc8; w2.y *= sc8; w2.z *= sc8; w2.w *= sc8;
    w3.x *= sc8; w3.y *= sc8; w3.z *= sc8; w3.w *= sc8;
    float b2s = ab2[h] * 0.125f;
    const float* Kb = Kp + (size_t)(h * RR + bat * TT) * D4 + dlo;
#pragma unroll
    for (int rsel = 0; rsel < 2; ++rsel) {
        int i = rsel ? iB : iA;
        int row = bat * TT + i;
        const float* qrow = Qp + (size_t)(h * RR + row) * D4 + dlo;
        float4 q0 = *(const float4*)(qrow + 0);
        float4 q1 = *(const float4*)(qrow + 4);
        float4 q2 = *(const float4*)(qrow + 8);
        float4 q3 = *(const float4*)(qrow + 12);
        for (int j = wv * 4 + sub; j <= i; j += 32) {
            const float* kj = Kb + (size_t)j * D4;
            float4 k0 = *(const float4*)(kj + 0);
            float4 k1 = *(const float4*)(kj + 4);
            float4 k2 = *(const float4*)(kj + 8);
            float4 k3 = *(const float4*)(kj + 12);
            float p = 0.f;
            p += sigm2(q0.x + k0.x) * w0.x + sigm2(q0.y + k0.y) * w0.y +
                 sigm2(q0.z + k0.z) * w0.z + sigm2(q0.w + k0.w) * w0.w;
            p += sigm2(q1.x + k1.x) * w1.x + sigm2(q1.y + k1.y) * w1.y +
                 sigm2(q1.z + k1.z) * w1.z + sigm2(q1.w + k1.w) * w1.w;
            p += sigm2(q2.x + k2.x) * w2.x + sigm2(q2.y + k2.y) * w2.y +
                 sigm2(q2.z + k2.z) * w2.z + sigm2(q2.w + k2.w) * w2.w;
            p += sigm2(q3.x + k3.x) * w3.x + sigm2(q3.y + k3.y) * w3.y +
                 sigm2(q3.z + k3.z) * w3.z + sigm2(q3.w + k3.w) * w3.w;
            p = row16_sum(p);                      // VALU-pipe reduce
            if ((lane & 15) == 0) sc[rsel][j] = p + b2s;
        }
    }
    __syncthreads();
    if ((wv & 3) == 0) {                           // softmax: waves 0 and 4
        int rsel = wv >> 2;
        int i = rsel ? iB : iA;
        float s0 = (lane <= i) ? sc[rsel][lane] : -1e30f;
        float s1 = (lane + 64 <= i) ? sc[rsel][lane + 64] : -1e30f;
        float m = wred_max(fmaxf(s0, s1));
        float e0 = (lane <= i) ? __expf(s0 - m) : 0.f;
        float e1 = (lane + 64 <= i) ? __expf(s1 - m) : 0.f;
        float inv = __builtin_amdgcn_rcpf(wred_sum(e0 + e1));
        sc[rsel][lane] = e0 * inv;
        sc[rsel][lane + 64] = e1 * inv;
    }
    __syncthreads();
    {   // PV: wave (rsel = wv>>2, wq = wv&3); lane -> (jo, s)
        int rsel = wv >> 2, wq = wv & 3;
        int i = rsel ? iB : iA;
        int jo = lane >> 4, s = lane & 15;
        int jstart = wq * 4 + jo;
        const float* vb = v + (size_t)(h * RR + bat * TT) * SS;
        float acc = 0.f;
        for (int j = jstart; j <= i; j += 16) acc += sc[rsel][j] * vb[j * SS + s];
        part[rsel][jstart][s] = acc;
    }
    __syncthreads();
    if (tid < 32) {
        int rsel = tid >> 4, s = tid & 15;
        int i = rsel ? iB : iA;
        int row = bat * TT + i;
        float a = 0.f;
#pragma unroll
        for (int k = 0; k < 16; ++k) a += part[rsel][k][s];
        o[row * CC + h * SS + s] = a;
    }
}

// ============ post: proj + residual + LN2 + FF + residual + LN3 ============
__global__ void __launch_bounds__(256) k_post(
    float* __restrict__ x, const float* __restrict__ o,
    const float* __restrict__ projW, const float* __restrict__ projb,
    const float* __restrict__ g2, const float* __restrict__ b2,
    const float* __restrict__ fW1, const float* __restrict__ fb1,
    const float* __restrict__ fW2, const float* __restrict__ fb2,
    const float* __restrict__ g3, const float* __restrict__ b3) {
    int row = blockIdx.x, tid = threadIdx.x;
    __shared__ float o_s[CC], s_x[CC], s_h[HID_], red[4][CC];
    if (tid < CC) o_s[tid] = o[row * CC + tid];
    __syncthreads();
    {   // proj: 4-way k-split, 2 accumulators
        int c = tid & 63, q = tid >> 6;
        float a0 = 0.f, a1 = 0.f;
        int k0 = q * 16;
#pragma unroll
        for (int k = 0; k < 16; k += 2) {
            a0 += o_s[k0 + k] * projW[(k0 + k) * CC + c];
            a1 += o_s[k0 + k + 1] * projW[(k0 + k + 1) * CC + c];
        }
        red[q][c] = a0 + a1;
    }
    __syncthreads();
    float xv = 0.f;
    if (tid < CC) {
        xv = x[row * CC + tid] + projb[tid] +
             red[0][tid] + red[1][tid] + red[2][tid] + red[3][tid];
        float m = wred_sum(xv) * (1.f / CC);
        float d = xv - m;
        float var = wred_sum(d * d) * (1.f / CC);
        s_x[tid] = d * rsqrtf(var + 1e-5f) * g2[tid] + b2[tid];
    }
    __syncthreads();
    {   // FF1: 256 hidden units, 2 accumulators
        float a0 = fb1[tid], a1 = 0.f;
#pragma unroll
        for (int k = 0; k < CC; k += 2) {
            a0 += s_x[k] * fW1[k * HID_ + tid];
            a1 += s_x[k + 1] * fW1[(k + 1) * HID_ + tid];
        }
        s_h[tid] = sigm(a0 + a1);
    }
    __syncthreads();
    {   // FF2: 4-way k-split, 2 accumulators
        int c = tid & 63, q = tid >> 6;
        float a0 = 0.f, a1 = 0.f;
#pragma unroll
        for (int k = q * 64; k < q * 64 + 64; k += 2) {
            a0 += s_h[k] * fW2[k * CC + c];
            a1 += s_h[k + 1] * fW2[(k + 1) * CC + c];
        }
        red[q][c] = a0 + a1;
    }
    __syncthreads();
    if (tid < CC) {
        float f = fb2[tid] + red[0][tid] + red[1][tid] + red[2][tid] + red[3][tid];
        float x2 = xv + f;
        float m = wred_sum(x2) * (1.f / CC);
        float d = x2 - m;
        float var = wred_sum(d * d) * (1.f / CC);
        x[row * CC + tid] = d * rsqrtf(var + 1e-5f) * g3[tid] + b3[tid];
    }
}

// ============ lm_head v6: 16 rows/block + non-temporal stores ============
// grid (16 col-slices, 16 row-groups) = 256 blocks; thread = 8 cols x 16 rows
__device__ __forceinline__ void lm_fma(float4& acc, float xs, float4 wv) {
    acc.x += xs * wv.x; acc.y += xs * wv.y;
    acc.z += xs * wv.z; acc.w += xs * wv.w;
}
__device__ __forceinline__ void nt_store4(float* p, float4 v) {
    f32x4 t;
    t.x = v.x; t.y = v.y; t.z = v.z; t.w = v.w;
    __builtin_nontemporal_store(t, (f32x4*)p);
}
__global__ void __launch_bounds__(256, 1) k_lmhead(const float* __restrict__ x,
                                                   const float* __restrict__ lmW,
                                                   const float* __restrict__ lmb,
                                                   float* __restrict__ out) {
    int tid = threadIdx.x;
    int r0 = blockIdx.y * 16;
    __shared__ __align__(16) float xT[CC][16];
    for (int e = tid; e < 16 * CC; e += 256) {
        int r = e >> 6, c = e & 63;
        xT[c][r] = x[(r0 + r) * CC + c];
    }
    __syncthreads();
    if (tid >= 250) return;
    int v8 = blockIdx.x * 2000 + tid * 8;
    float4 b0 = *(const float4*)(lmb + v8);
    float4 b1 = *(const float4*)(lmb + v8 + 4);
    float4 a0[16], a1[16];
#pragma unroll
    for (int r = 0; r < 16; ++r) { a0[r] = b0; a1[r] = b1; }
#pragma unroll 2
    for (int c = 0; c < CC; ++c) {
        float4 w0 = *(const float4*)(lmW + (size_t)c * VV + v8);
        float4 w1 = *(const float4*)(lmW + (size_t)c * VV + v8 + 4);
        float4 xa = *(const float4*)&xT[c][0];
        float4 xb = *(const float4*)&xT[c][4];
        float4 xc = *(const float4*)&xT[c][8];
        float4 xd = *(const float4*)&xT[c][12];
        lm_fma(a0[0],  xa.x, w0); lm_fma(a1[0],  xa.x, w1);
        lm_fma(a0[1],  xa.y, w0); lm_fma(a1[1],  xa.y, w1);
        lm_fma(a0[2],  xa.z, w0); lm_fma(a1[2],  xa.z, w1);
        lm_fma(a0[3],  xa.w, w0); lm_fma(a1[3],  xa.w, w1);
        lm_fma(a0[4],  xb.x, w0); lm_fma(a1[4],  xb.x, w1);
        lm_fma(a0[5],  xb.y, w0); lm_fma(a1[5],  xb.y, w1);
        lm_fma(a0[6],  xb.z, w0); lm_fma(a1[6],  xb.z, w1);
        lm_fma(a0[7],  xb.w, w0); lm_fma(a1[7],  xb.w, w1);
        lm_fma(a0[8],  xc.x, w0); lm_fma(a1[8],  xc.x, w1);
        lm_fma(a0[9],  xc.y, w0); lm_fma(a1[9],  xc.y, w1);
        lm_fma(a0[10], xc.z, w0); lm_fma(a1[10], xc.z, w1);
        lm_fma(a0[11], xc.w, w0); lm_fma(a1[11], xc.w, w1);
        lm_fma(a0[12], xd.x, w0); lm_fma(a1[12], xd.x, w1);
        lm_fma(a0[13], xd.y, w0); lm_fma(a1[13], xd.y, w1);
        lm_fma(a0[14], xd.z, w0); lm_fma(a1[14], xd.z, w1);
        lm_fma(a0[15], xd.w, w0); lm_fma(a1[15], xd.w, w1);
    }
#pragma unroll
    for (int r = 0; r < 16; ++r) {
        float* ob = out + (size_t)(r0 + r) * VV + v8;
        nt_store4(ob, a0[r]);
        nt_store4(ob + 4, a1[r]);
    }
}

extern "C" void kernel_launch(void* const* d_in, const int* in_sizes, int n_in,
                              void* d_out, int out_size, void* d_ws, size_t ws_size,
                              hipStream_t stream) {
    const int*   idx   = (const int*)d_in[0];
    const float* tok   = (const float*)d_in[1];
    const float* petab = (const float*)d_in[2];
    const float* peW1  = (const float*)d_in[3];
    const float* peb1  = (const float*)d_in[4];
    const float* peW2  = (const float*)d_in[5];
    const float* peb2  = (const float*)d_in[6];
    const float* peg   = (const float*)d_in[7];
    const float* pebb  = (const float*)d_in[8];
    const float* ln1g  = (const float*)d_in[9];
    const float* ln1b  = (const float*)d_in[10];
    const float* attW1 = (const float*)d_in[11];
    const float* attb1 = (const float*)d_in[12];
    const float* attW2 = (const float*)d_in[13];
    const float* attb2 = (const float*)d_in[14];
    const float* valW  = (const float*)d_in[15];
    const float* projW = (const float*)d_in[16];
    const float* projb = (const float*)d_in[17];
    const float* ln2g  = (const float*)d_in[18];
    const float* ln2b  = (const float*)d_in[19];
    const float* ffW1  = (const float*)d_in[20];
    const float* ffb1  = (const float*)d_in[21];
    const float* ffW2  = (const float*)d_in[22];
    const float* ffb2  = (const float*)d_in[23];
    const float* ln3g  = (const float*)d_in[24];
    const float* ln3b  = (const float*)d_in[25];
    const float* lmW   = (const float*)d_in[26];
    const float* lmb   = (const float*)d_in[27];

    float* ws  = (float*)d_ws;
    float* x   = ws;                  // 16384
    float* pos = ws + 16384;          // 32768
    float* v   = ws + 49152;          // 16384
    float* o   = ws + 65536;          // 16384
    float* Kp  = ws + 81920;          // 262144 (pre-scaled, +b1)
    float* Qp  = ws + 344064;         // 262144 (pre-scaled)

    k_embed_pos<<<768, CC, 0, stream>>>(idx, tok, petab, peW1, peb1, peW2, peb2,
                                        peg, pebb, x, pos);
    for (int p = 0; p < NPE_; p++) {
        k_stageA<<<512, 256, 0, stream>>>(x, pos + p * TT * CC, ln1g, ln1b,
                                          attW1, attb1, valW, Kp, Qp, v);
        k_att4<<<512, 512, 0, stream>>>(Kp, Qp, v, attW2, attb2, o);
        k_post<<<RR, 256, 0, stream>>>(x, o, projW, projb, ln2g, ln2b,
                                       ffW1, ffb1, ffW2, ffb2, ln3g, ln3b);
    }
    k_lmhead<<<dim3(16, 16), 256, 0, stream>>>(x, lmW, lmb, (float*)d_out);
}

// Round 29
// 133.263 us; speedup vs baseline: 1.0791x; 1.0791x over previous
//
#include <hip/hip_runtime.h>

// Model dims (fixed by the problem)
#define TT    128
#define CC    64
#define HH    4
#define SS    16
#define D4    256     // 4*C
#define HID_  256
#define VV    32000
#define NPE_  4
#define RR    256     // B*T
#define LOG2E 1.44269504f

typedef float f32x4 __attribute__((ext_vector_type(4)));

__device__ __forceinline__ float wred_sum(float v) {
#pragma unroll
    for (int off = 32; off; off >>= 1) v += __shfl_xor(v, off, 64);
    return v;
}
__device__ __forceinline__ float wred_max(float v) {
#pragma unroll
    for (int off = 32; off; off >>= 1) v = fmaxf(v, __shfl_xor(v, off, 64));
    return v;
}
__device__ __forceinline__ float sigm(float x) {
    return __builtin_amdgcn_rcpf(1.f + exp2f(-x * LOG2E));
}
__device__ __forceinline__ float sigm2(float t) {   // input pre-scaled by log2e
    return __builtin_amdgcn_rcpf(1.f + exp2f(-t));
}

// VALU-pipe 16-lane sum reduce via DPP row rotates (no DS ops)
#define DPP_ADD(v, ctrl)                                                       \
    v += __int_as_float(__builtin_amdgcn_update_dpp(                           \
        0, __float_as_int(v), ctrl, 0xF, 0xF, true))
__device__ __forceinline__ float row16_sum(float v) {
    DPP_ADD(v, 0x128);   // row_ror:8
    DPP_ADD(v, 0x124);   // row_ror:4
    DPP_ADD(v, 0x122);   // row_ror:2
    DPP_ADD(v, 0x121);   // row_ror:1
    return v;            // all 16 lanes hold the row sum
}

// ============ embed + all positional embeddings (one launch) ============
__global__ void k_embed_pos(const int* __restrict__ idx, const float* __restrict__ tok,
                            const float* __restrict__ pe_tab, const float* __restrict__ W1,
                            const float* __restrict__ b1, const float* __restrict__ W2,
                            const float* __restrict__ b2, const float* __restrict__ g,
                            const float* __restrict__ bb,
                            float* __restrict__ x, float* __restrict__ pos) {
    int blk = blockIdx.x, c = threadIdx.x;
    if (blk >= 512) {
        int r = blk - 512;
        x[r * CC + c] = tok[idx[r] * CC + c];
        return;
    }
    int p = blk >> 7, t = blk & 127;
    __shared__ float s_pe[CC], s_h[CC];
    s_pe[c] = pe_tab[(p * TT + t) * CC + c];
    __syncthreads();
    const float* w1 = W1 + p * CC * CC;
    float a = b1[p * CC + c];
    for (int k = 0; k < CC; k++) a += s_pe[k] * w1[k * CC + c];
    s_h[c] = sigm(a);
    __syncthreads();
    const float* w2 = W2 + p * CC * CC;
    float o = b2[p * CC + c];
    for (int k = 0; k < CC; k++) o += s_h[k] * w2[k * CC + c];
    float m = wred_sum(o) * (1.f / CC);
    float d = o - m;
    float var = wred_sum(d * d) * (1.f / CC);
    pos[(p * TT + t) * CC + c] =
        d * rsqrtf(var + 1e-5f) * g[p * CC + c] + bb[p * CC + c];
}

// ============ stage A v3b: 4 rows/block, 512 blocks; spill-guarded ==========
// rg = blk&63 (4 rows), kq = (blk>>6)&1, h = blk>>7
__global__ void __launch_bounds__(256, 4) k_stageA(
    const float* __restrict__ x, const float* __restrict__ pos_p,
    const float* __restrict__ ln1g, const float* __restrict__ ln1b,
    const float* __restrict__ attW1, const float* __restrict__ ab1,
    const float* __restrict__ valW,
    float* __restrict__ Kp, float* __restrict__ Qp, float* __restrict__ v) {
    int blk = blockIdx.x, tid = threadIdx.x;
    int lane = tid & 63, wv = tid >> 6;
    int rg = blk & 63, kq = (blk >> 6) & 1, h = blk >> 7;
    int r0 = rg * 4;
    __shared__ __align__(16) float x1[4][128];
    {   // LN1: wave wv handles row r0+wv
        float xv = x[(r0 + wv) * CC + lane];
        float m = wred_sum(xv) * (1.f / CC);
        float d = xv - m;
        float var = wred_sum(d * d) * (1.f / CC);
        x1[wv][64 + lane] = d * rsqrtf(var + 1e-5f) * ln1g[lane] + ln1b[lane];
    }
    {   // pos half: 256 threads = 4 rows x 64 cols
        int rr = tid >> 6, cc = tid & 63;
        int t = (r0 + rr) & (TT - 1);
        x1[rr][cc] = pos_p[t * CC + cc];
    }
    __syncthreads();
    const float* w = attW1 + (h * D4 + kq * 128) * D4 + tid;
    float a0 = 0, a1 = 0, a2 = 0, a3 = 0;
#pragma unroll 2
    for (int c = 0; c < 128; c += 4) {
        float4 xr0 = *(const float4*)&x1[0][c];
        float4 xr1 = *(const float4*)&x1[1][c];
        float4 xr2 = *(const float4*)&x1[2][c];
        float4 xr3 = *(const float4*)&x1[3][c];
        float w0 = w[(size_t)(c + 0) * D4];
        float w1 = w[(size_t)(c + 1) * D4];
        float w2 = w[(size_t)(c + 2) * D4];
        float w3 = w[(size_t)(c + 3) * D4];
        a0 += xr0.x * w0 + xr0.y * w1 + xr0.z * w2 + xr0.w * w3;
        a1 += xr1.x * w0 + xr1.y * w1 + xr1.z * w2 + xr1.w * w3;
        a2 += xr2.x * w0 + xr2.y * w1 + xr2.z * w2 + xr2.w * w3;
        a3 += xr3.x * w0 + xr3.y * w1 + xr3.z * w2 + xr3.w * w3;
    }
    float badd = kq ? 0.f : ab1[h * D4 + tid];   // fold b1 into K
    float* outKQ = kq ? Qp : Kp;
    outKQ[(h * RR + r0 + 0) * D4 + tid] = (a0 + badd) * LOG2E;
    outKQ[(h * RR + r0 + 1) * D4 + tid] = (a1 + badd) * LOG2E;
    outKQ[(h * RR + r0 + 2) * D4 + tid] = (a2 + badd) * LOG2E;
    outKQ[(h * RR + r0 + 3) * D4 + tid] = (a3 + badd) * LOG2E;
    if (kq == 0 && tid < 64) {   // V: 4 rows x 16 s
        int rr = tid >> 4, s = tid & 15;
        const float* wvw = valW + h * CC * SS;
        float a = 0.f;
#pragma unroll 8
        for (int k = 0; k < CC; k++) a += x1[rr][64 + k] * wvw[k * SS + s];
        v[(h * RR + r0 + rr) * SS + s] = a;
    }
}

// ============ att4: causal-balanced row pairs (i, 127-i), 16 waves/CU ======
// 512 blocks x 512 thr; pairIdx = bid&63, bat = (bid>>6)&1, h = bid>>7
__global__ void __launch_bounds__(512) k_att4(
    const float* __restrict__ Kp, const float* __restrict__ Qp,
    const float* __restrict__ v,
    const float* __restrict__ aw2, const float* __restrict__ ab2,
    float* __restrict__ o) {
    int bid = blockIdx.x;
    int pairIdx = bid & 63, bat = (bid >> 6) & 1, h = bid >> 7;
    int iA = pairIdx, iB = 127 - pairIdx;
    int tid = threadIdx.x, lane = tid & 63, wv = tid >> 6;   // wv 0..7
    __shared__ float sc[2][TT];
    __shared__ float part[2][16][17];
    int sub = lane >> 4;                       // j sub-slot within wave
    int dlo = (lane & 15) * 16;                // 16 d-components per lane
    const float* wrow = aw2 + h * D4 + dlo;
    float4 w0 = *(const float4*)(wrow + 0);
    float4 w1 = *(const float4*)(wrow + 4);
    float4 w2 = *(const float4*)(wrow + 8);
    float4 w3 = *(const float4*)(wrow + 12);
    const float sc8 = 0.125f;
    w0.x *= sc8; w0.y *= sc8; w0.z *= sc8; w0.w *= sc8;
    w1.x *= sc8; w1.y *= sc8; w1.z *= sc8; w1.w *= sc8;
    w2.x *= sc8; w2.y *= sc8; w2.z *= sc8; w2.w *= sc8;
    w3.x *= sc8; w3.y *= sc8; w3.z *= sc8; w3.w *= sc8;
    float b2s = ab2[h] * 0.125f;
    const float* Kb = Kp + (size_t)(h * RR + bat * TT) * D4 + dlo;
#pragma unroll
    for (int rsel = 0; rsel < 2; ++rsel) {
        int i = rsel ? iB : iA;
        int row = bat * TT + i;
        const float* qrow = Qp + (size_t)(h * RR + row) * D4 + dlo;
        float4 q0 = *(const float4*)(qrow + 0);
        float4 q1 = *(const float4*)(qrow + 4);
        float4 q2 = *(const float4*)(qrow + 8);
        float4 q3 = *(const float4*)(qrow + 12);
        for (int j = wv * 4 + sub; j <= i; j += 32) {
            const float* kj = Kb + (size_t)j * D4;
            float4 k0 = *(const float4*)(kj + 0);
            float4 k1 = *(const float4*)(kj + 4);
            float4 k2 = *(const float4*)(kj + 8);
            float4 k3 = *(const float4*)(kj + 12);
            float p = 0.f;
            p += sigm2(q0.x + k0.x) * w0.x + sigm2(q0.y + k0.y) * w0.y +
                 sigm2(q0.z + k0.z) * w0.z + sigm2(q0.w + k0.w) * w0.w;
            p += sigm2(q1.x + k1.x) * w1.x + sigm2(q1.y + k1.y) * w1.y +
                 sigm2(q1.z + k1.z) * w1.z + sigm2(q1.w + k1.w) * w1.w;
            p += sigm2(q2.x + k2.x) * w2.x + sigm2(q2.y + k2.y) * w2.y +
                 sigm2(q2.z + k2.z) * w2.z + sigm2(q2.w + k2.w) * w2.w;
            p += sigm2(q3.x + k3.x) * w3.x + sigm2(q3.y + k3.y) * w3.y +
                 sigm2(q3.z + k3.z) * w3.z + sigm2(q3.w + k3.w) * w3.w;
            p = row16_sum(p);                      // VALU-pipe reduce
            if ((lane & 15) == 0) sc[rsel][j] = p + b2s;
        }
    }
    __syncthreads();
    if ((wv & 3) == 0) {                           // softmax: waves 0 and 4
        int rsel = wv >> 2;
        int i = rsel ? iB : iA;
        float s0 = (lane <= i) ? sc[rsel][lane] : -1e30f;
        float s1 = (lane + 64 <= i) ? sc[rsel][lane + 64] : -1e30f;
        float m = wred_max(fmaxf(s0, s1));
        float e0 = (lane <= i) ? __expf(s0 - m) : 0.f;
        float e1 = (lane + 64 <= i) ? __expf(s1 - m) : 0.f;
        float inv = __builtin_amdgcn_rcpf(wred_sum(e0 + e1));
        sc[rsel][lane] = e0 * inv;
        sc[rsel][lane + 64] = e1 * inv;
    }
    __syncthreads();
    {   // PV: wave (rsel = wv>>2, wq = wv&3); lane -> (jo, s)
        int rsel = wv >> 2, wq = wv & 3;
        int i = rsel ? iB : iA;
        int jo = lane >> 4, s = lane & 15;
        int jstart = wq * 4 + jo;
        const float* vb = v + (size_t)(h * RR + bat * TT) * SS;
        float acc = 0.f;
        for (int j = jstart; j <= i; j += 16) acc += sc[rsel][j] * vb[j * SS + s];
        part[rsel][jstart][s] = acc;
    }
    __syncthreads();
    if (tid < 32) {
        int rsel = tid >> 4, s = tid & 15;
        int i = rsel ? iB : iA;
        int row = bat * TT + i;
        float a = 0.f;
#pragma unroll
        for (int k = 0; k < 16; ++k) a += part[rsel][k][s];
        o[row * CC + h * SS + s] = a;
    }
}

// ============ post: proj + residual + LN2 + FF + residual + LN3 ============
__global__ void __launch_bounds__(256) k_post(
    float* __restrict__ x, const float* __restrict__ o,
    const float* __restrict__ projW, const float* __restrict__ projb,
    const float* __restrict__ g2, const float* __restrict__ b2,
    const float* __restrict__ fW1, const float* __restrict__ fb1,
    const float* __restrict__ fW2, const float* __restrict__ fb2,
    const float* __restrict__ g3, const float* __restrict__ b3) {
    int row = blockIdx.x, tid = threadIdx.x;
    __shared__ float o_s[CC], s_x[CC], s_h[HID_], red[4][CC];
    if (tid < CC) o_s[tid] = o[row * CC + tid];
    __syncthreads();
    {   // proj: 4-way k-split, 2 accumulators
        int c = tid & 63, q = tid >> 6;
        float a0 = 0.f, a1 = 0.f;
        int k0 = q * 16;
#pragma unroll
        for (int k = 0; k < 16; k += 2) {
            a0 += o_s[k0 + k] * projW[(k0 + k) * CC + c];
            a1 += o_s[k0 + k + 1] * projW[(k0 + k + 1) * CC + c];
        }
        red[q][c] = a0 + a1;
    }
    __syncthreads();
    float xv = 0.f;
    if (tid < CC) {
        xv = x[row * CC + tid] + projb[tid] +
             red[0][tid] + red[1][tid] + red[2][tid] + red[3][tid];
        float m = wred_sum(xv) * (1.f / CC);
        float d = xv - m;
        float var = wred_sum(d * d) * (1.f / CC);
        s_x[tid] = d * rsqrtf(var + 1e-5f) * g2[tid] + b2[tid];
    }
    __syncthreads();
    {   // FF1: 256 hidden units, 2 accumulators
        float a0 = fb1[tid], a1 = 0.f;
#pragma unroll
        for (int k = 0; k < CC; k += 2) {
            a0 += s_x[k] * fW1[k * HID_ + tid];
            a1 += s_x[k + 1] * fW1[(k + 1) * HID_ + tid];
        }
        s_h[tid] = sigm(a0 + a1);
    }
    __syncthreads();
    {   // FF2: 4-way k-split, 2 accumulators
        int c = tid & 63, q = tid >> 6;
        float a0 = 0.f, a1 = 0.f;
#pragma unroll
        for (int k = q * 64; k < q * 64 + 64; k += 2) {
            a0 += s_h[k] * fW2[k * CC + c];
            a1 += s_h[k + 1] * fW2[(k + 1) * CC + c];
        }
        red[q][c] = a0 + a1;
    }
    __syncthreads();
    if (tid < CC) {
        float f = fb2[tid] + red[0][tid] + red[1][tid] + red[2][tid] + red[3][tid];
        float x2 = xv + f;
        float m = wred_sum(x2) * (1.f / CC);
        float d = x2 - m;
        float var = wred_sum(d * d) * (1.f / CC);
        x[row * CC + tid] = d * rsqrtf(var + 1e-5f) * g3[tid] + b3[tid];
    }
}

// ============ lm_head v7: 16 rows/block, 512 thr (8 waves/CU), named accs ====
// grid (16 col-slices, 16 row-groups) = 256 blocks; thread = 4 cols x 16 rows
__device__ __forceinline__ void lm_fma(float4& acc, float xs, float4 wv) {
    acc.x += xs * wv.x; acc.y += xs * wv.y;
    acc.z += xs * wv.z; acc.w += xs * wv.w;
}
__device__ __forceinline__ void nt_store4(float* p, float4 v) {
    f32x4 t;
    t.x = v.x; t.y = v.y; t.z = v.z; t.w = v.w;
    __builtin_nontemporal_store(t, (f32x4*)p);
}
__global__ void __launch_bounds__(512, 1) k_lmhead(const float* __restrict__ x,
                                                   const float* __restrict__ lmW,
                                                   const float* __restrict__ lmb,
                                                   float* __restrict__ out) {
    int tid = threadIdx.x;
    int r0 = blockIdx.y * 16;
    __shared__ __align__(16) float xT[CC][16];
    for (int e = tid; e < 16 * CC; e += 512) {
        int r = e >> 6, c = e & 63;
        xT[c][r] = x[(r0 + r) * CC + c];
    }
    __syncthreads();
    if (tid >= 500) return;
    int v4c = blockIdx.x * 2000 + tid * 4;
    float4 bb = *(const float4*)(lmb + v4c);
    float4 r0a = bb, r1a = bb, r2a = bb, r3a = bb;
    float4 r4a = bb, r5a = bb, r6a = bb, r7a = bb;
    float4 r8a = bb, r9a = bb, r10a = bb, r11a = bb;
    float4 r12a = bb, r13a = bb, r14a = bb, r15a = bb;
#pragma unroll 2
    for (int c = 0; c < CC; ++c) {
        float4 w = *(const float4*)(lmW + (size_t)c * VV + v4c);
        float4 xa = *(const float4*)&xT[c][0];
        float4 xb = *(const float4*)&xT[c][4];
        float4 xc = *(const float4*)&xT[c][8];
        float4 xd = *(const float4*)&xT[c][12];
        lm_fma(r0a,  xa.x, w); lm_fma(r1a,  xa.y, w);
        lm_fma(r2a,  xa.z, w); lm_fma(r3a,  xa.w, w);
        lm_fma(r4a,  xb.x, w); lm_fma(r5a,  xb.y, w);
        lm_fma(r6a,  xb.z, w); lm_fma(r7a,  xb.w, w);
        lm_fma(r8a,  xc.x, w); lm_fma(r9a,  xc.y, w);
        lm_fma(r10a, xc.z, w); lm_fma(r11a, xc.w, w);
        lm_fma(r12a, xd.x, w); lm_fma(r13a, xd.y, w);
        lm_fma(r14a, xd.z, w); lm_fma(r15a, xd.w, w);
    }
    float* ob = out + (size_t)r0 * VV + v4c;
    nt_store4(ob + 0 * VV, r0a);  nt_store4(ob + 1 * VV, r1a);
    nt_store4(ob + 2 * VV, r2a);  nt_store4(ob + 3 * VV, r3a);
    nt_store4(ob + 4 * VV, r4a);  nt_store4(ob + 5 * VV, r5a);
    nt_store4(ob + 6 * VV, r6a);  nt_store4(ob + 7 * VV, r7a);
    nt_store4(ob + 8 * VV, r8a);  nt_store4(ob + 9 * VV, r9a);
    nt_store4(ob + 10 * VV, r10a); nt_store4(ob + 11 * VV, r11a);
    nt_store4(ob + 12 * VV, r12a); nt_store4(ob + 13 * VV, r13a);
    nt_store4(ob + 14 * VV, r14a); nt_store4(ob + 15 * VV, r15a);
}

extern "C" void kernel_launch(void* const* d_in, const int* in_sizes, int n_in,
                              void* d_out, int out_size, void* d_ws, size_t ws_size,
                              hipStream_t stream) {
    const int*   idx   = (const int*)d_in[0];
    const float* tok   = (const float*)d_in[1];
    const float* petab = (const float*)d_in[2];
    const float* peW1  = (const float*)d_in[3];
    const float* peb1  = (const float*)d_in[4];
    const float* peW2  = (const float*)d_in[5];
    const float* peb2  = (const float*)d_in[6];
    const float* peg   = (const float*)d_in[7];
    const float* pebb  = (const float*)d_in[8];
    const float* ln1g  = (const float*)d_in[9];
    const float* ln1b  = (const float*)d_in[10];
    const float* attW1 = (const float*)d_in[11];
    const float* attb1 = (const float*)d_in[12];
    const float* attW2 = (const float*)d_in[13];
    const float* attb2 = (const float*)d_in[14];
    const float* valW  = (const float*)d_in[15];
    const float* projW = (const float*)d_in[16];
    const float* projb = (const float*)d_in[17];
    const float* ln2g  = (const float*)d_in[18];
    const float* ln2b  = (const float*)d_in[19];
    const float* ffW1  = (const float*)d_in[20];
    const float* ffb1  = (const float*)d_in[21];
    const float* ffW2  = (const float*)d_in[22];
    const float* ffb2  = (const float*)d_in[23];
    const float* ln3g  = (const float*)d_in[24];
    const float* ln3b  = (const float*)d_in[25];
    const float* lmW   = (const float*)d_in[26];
    const float* lmb   = (const float*)d_in[27];

    float* ws  = (float*)d_ws;
    float* x   = ws;                  // 16384
    float* pos = ws + 16384;          // 32768
    float* v   = ws + 49152;          // 16384
    float* o   = ws + 65536;          // 16384
    float* Kp  = ws + 81920;          // 262144 (pre-scaled, +b1)
    float* Qp  = ws + 344064;         // 262144 (pre-scaled)

    k_embed_pos<<<768, CC, 0, stream>>>(idx, tok, petab, peW1, peb1, peW2, peb2,
                                        peg, pebb, x, pos);
    for (int p = 0; p < NPE_; p++) {
        k_stageA<<<512, 256, 0, stream>>>(x, pos + p * TT * CC, ln1g, ln1b,
                                          attW1, attb1, valW, Kp, Qp, v);
        k_att4<<<512, 512, 0, stream>>>(Kp, Qp, v, attW2, attb2, o);
        k_post<<<RR, 256, 0, stream>>>(x, o, projW, projb, ln2g, ln2b,
                                       ffW1, ffb1, ffW2, ffb2, ln3g, ln3b);
    }
    k_lmhead<<<dim3(16, 16), 512, 0, stream>>>(x, lmW, lmb, (float*)d_out);
}